// Round 10
// baseline (181.145 us; speedup 1.0000x reference)
//
#include <hip/hip_runtime.h>
#include <hip/hip_bf16.h>

#define LB 2048
#define DB 256
#define HB 8
#define KB 64
#define BH 32   // B*H

typedef __attribute__((ext_vector_type(8))) short short8;
typedef __attribute__((ext_vector_type(4))) short short4v;
typedef __attribute__((ext_vector_type(4))) float floatx4;
typedef __attribute__((ext_vector_type(4))) int   int4v;

static __device__ __forceinline__ short bfbits(float f) {
    __hip_bfloat16 h = __float2bfloat16(f);
    return *reinterpret_cast<short*>(&h);
}

static __device__ __forceinline__ void keep8(const short8& v) {
    int4v k = __builtin_bit_cast(int4v, v);
    asm volatile("" :: "v"(k.x), "v"(k.y), "v"(k.z), "v"(k.w));
}

// Fragment-order formula (16-row tile, element (l, k)):
//   pos = ((k>>3)*16 + (l&15))*8 + (k&7)

// ---------------- prep: x fp32 [8192][256] -> bf16 fragment tiles [512][4096]
__global__ __launch_bounds__(256) void prep_x(const float* __restrict__ x,
                                              __hip_bfloat16* __restrict__ xb)
{
    const int t = blockIdx.x;                 // 16-row tile
#pragma unroll
    for (int cc = 0; cc < 2; ++cc) {
        const int c   = threadIdx.x + cc * 256;   // chunk 0..511
        const int l   = c & 15;
        const int ksg = c >> 4;                   // k = ksg*8 ..
        const float* src = x + (size_t)(t * 16 + l) * DB + ksg * 8;
        short8 o;
#pragma unroll
        for (int e = 0; e < 8; ++e) o[e] = bfbits(src[e]);
        *(reinterpret_cast<short8*>(xb + (size_t)t * 4096) + c) = o;
    }
}

// ---------------- prep: W [256][512] -> transposed bf16 fragment tiles
__global__ __launch_bounds__(256) void prep_w(const float* __restrict__ Wq,
                                              const float* __restrict__ Wk,
                                              __hip_bfloat16* __restrict__ wb)
{
    const int blk = blockIdx.x;               // 0..63
    const float* W = (blk & 32) ? Wk : Wq;
    const int nbase = (blk & 31) * 16;
#pragma unroll
    for (int cc = 0; cc < 2; ++cc) {
        const int c  = threadIdx.x + cc * 256;
        const int n  = nbase + (c & 15);
        const int k0 = (c >> 4) * 8;
        short8 o;
#pragma unroll
        for (int e = 0; e < 8; ++e) o[e] = bfbits(W[(size_t)(k0 + e) * 512 + n]);
        *(reinterpret_cast<short8*>(wb + (size_t)blk * 4096) + c) = o;
    }
}

// ---------------- projection GEMM via MFMA (R7, unchanged)
__global__ __launch_bounds__(256) void proj_mfma(
    const __hip_bfloat16* __restrict__ xb, const __hip_bfloat16* __restrict__ wb,
    const float* __restrict__ bq, const float* __restrict__ bk,
    __hip_bfloat16* __restrict__ qout, __hip_bfloat16* __restrict__ kout)
{
    const int rt   = blockIdx.x;              // 64-row block
    const int cg   = blockIdx.y;              // 128-col group
    const int wave = threadIdx.x >> 6;
    const int lane = threadIdx.x & 63;
    const int kg   = lane >> 4;
    const int l    = lane & 15;

    const short8* xp = reinterpret_cast<const short8*>(xb)
                     + (size_t)(rt * 4 + wave) * 512 + lane;
    short8 a[8];
#pragma unroll
    for (int kb = 0; kb < 8; ++kb) a[kb] = xp[kb * 64];

    const int b_     = rt >> 5;               // batch
    const int tile_l = (rt & 31) * 4 + wave;  // 16-row tile index within [B,L]
    const int gct0   = cg * 8;
    const short8* wp = reinterpret_cast<const short8*>(wb) + lane;

    short8 wA[8], wB[8];
#pragma unroll
    for (int kb = 0; kb < 8; ++kb) wA[kb] = wp[(size_t)(gct0 * 8 + kb) * 64];

#define PROJ_STEP(CURW, NXTW, CT)                                                     \
    {                                                                                 \
        if ((CT) < 7) {                                                               \
            _Pragma("unroll")                                                         \
            for (int kb = 0; kb < 8; ++kb)                                            \
                NXTW[kb] = wp[(size_t)((gct0 + (CT) + 1) * 8 + kb) * 64];             \
        }                                                                             \
        floatx4 acc = {0.f, 0.f, 0.f, 0.f};                                           \
        _Pragma("unroll")                                                             \
        for (int kb = 0; kb < 8; ++kb)                                                \
            acc = __builtin_amdgcn_mfma_f32_16x16x32_bf16(CURW[kb], a[kb], acc, 0, 0, 0); \
        const int gct = gct0 + (CT);                                                  \
        const int m   = gct >> 5;                                                     \
        const int ctm = gct & 31;                                                     \
        const int h   = ctm >> 2;                                                     \
        const float bias = (m ? bk : bq)[h];                                          \
        __hip_bfloat16* outp = m ? kout : qout;                                       \
        const size_t dst = ((size_t)(b_ * HB + h) * 128 + tile_l) * 1024              \
                         + (size_t)(((ctm & 3) * 2 + (kg >> 1)) * 16 + l) * 8         \
                         + (kg & 1) * 4;                                              \
        short4v o;                                                                    \
        _Pragma("unroll")                                                             \
        for (int r = 0; r < 4; ++r) o[r] = bfbits(acc[r] + bias);                     \
        *reinterpret_cast<short4v*>(outp + dst) = o;                                  \
    }

    PROJ_STEP(wA, wB, 0)
    PROJ_STEP(wB, wA, 1)
    PROJ_STEP(wA, wB, 2)
    PROJ_STEP(wB, wA, 3)
    PROJ_STEP(wA, wB, 4)
    PROJ_STEP(wB, wA, 5)
    PROJ_STEP(wA, wB, 6)
    PROJ_STEP(wB, wA, 7)
#undef PROJ_STEP
}

// ---------------- attention (R7 structure) with ablation template
// V=0 full | V=1 no tab ds_read | V=2 no MFMA | V=3 no u-math | V=4 loads hoisted
template<int V>
__global__ __launch_bounds__(256) void attn_k(
    const __hip_bfloat16* __restrict__ qb, const __hip_bfloat16* __restrict__ kb,
    const float* __restrict__ prior_mean, const float* __restrict__ log_prior_std,
    float* __restrict__ outp)
{
    __shared__ float tab[4096];       // 0.125 * prior(d), d = idx - 2047
    __shared__ float2 comb[4][64];

    const int tile = blockIdx.x;          // 64-row q tile, 0..31
    const int bh   = blockIdx.y;          // 0..31
    const int h    = bh & 7;
    const int wave = threadIdx.x >> 6;
    const int lane = threadIdx.x & 63;
    const int lrow = lane & 15;
    const int kg   = lane >> 4;
    const int i0   = tile * 64;

    {
        const float mu        = prior_mean[h];
        const float inv_sigma = __expf(-log_prior_std[h]);
        const float coef = 0.125f * inv_sigma * (1.0f / 2.5066282f);
        for (int j = threadIdx.x; j < 4095; j += 256) {
            const float t = ((float)(j - 2047) - mu) * inv_sigma;
            tab[j] = coef * __expf(-0.5f * t * t);
        }
    }
    __syncthreads();

    if constexpr (V == 1) {           // keep tab build alive though unread
        float dk = tab[threadIdx.x];
        asm volatile("" :: "v"(dk));
    }

    const size_t planebase = (size_t)bh * LB * KB;

    const short8* qp = reinterpret_cast<const short8*>(qb + planebase)
                     + (size_t)(i0 >> 4) * 128 + lane;
    short8 a0[4], a1[4];
#pragma unroll
    for (int g = 0; g < 4; ++g) { a0[g] = qp[g * 128]; a1[g] = qp[g * 128 + 64]; }

    if constexpr (V == 2) {           // q loads alive though MFMA removed
#pragma unroll
        for (int g = 0; g < 4; ++g) { keep8(a0[g]); keep8(a1[g]); }
    }

    const int KW0 = wave * 512;
    const short8* kp = reinterpret_cast<const short8*>(kb + planebase)
                     + (size_t)(KW0 >> 4) * 128 + lane;

    float se[4][4], sw[4][4];
#pragma unroll
    for (int g = 0; g < 4; ++g)
#pragma unroll
        for (int r = 0; r < 4; ++r) { se[g][r] = 0.f; sw[g][r] = 0.f; }

    const int lo = lrow - 4 * kg;
    const float* tb = &tab[2047 + lo - i0 + KW0];
    const float Dl = (float)(lo - i0 + KW0);
    const float prc  = (float)(lo + 9) * 7.8e-4f;   // V1 stand-in prior
    const float accs = Dl * 1e-7f;                  // V2 stand-in score

    short8 k0[4], k1[4];
    if constexpr (V == 4) {           // hoist loads: one tile reused all steps
#pragma unroll
        for (int c = 0; c < 4; ++c) {
            const short8* p = kp + (size_t)c * 128;
            k0[c] = p[0];
            k1[c] = p[64];
        }
    }

#pragma unroll 2
    for (int st = 0; st < 8; ++st) {      // 8 steps x 64 keys
        if constexpr (V != 4) {
#pragma unroll
            for (int c = 0; c < 4; ++c) {
                const short8* p = kp + (size_t)(st * 4 + c) * 128;
                k0[c] = p[0];
                k1[c] = p[64];
            }
        }
        if constexpr (V == 2) {
#pragma unroll
            for (int c = 0; c < 4; ++c) { keep8(k0[c]); keep8(k1[c]); }
        }
#pragma unroll
        for (int c = 0; c < 4; ++c) {
#pragma unroll
            for (int g = 0; g < 4; ++g) {
                floatx4 acc;
                if constexpr (V == 2) {
                    acc = (floatx4){accs, accs, accs, accs};
                } else {
                    floatx4 z = {0.f, 0.f, 0.f, 0.f};
                    z = __builtin_amdgcn_mfma_f32_16x16x32_bf16(a0[g], k0[c], z, 0, 0, 0);
                    acc = __builtin_amdgcn_mfma_f32_16x16x32_bf16(a1[g], k1[c], z, 0, 0, 0);
                }
                const int   off = st * 64 + 16 * (c - g);
                const float* t3 = tb + off;
                const float D0  = Dl + (float)off;
#pragma unroll
                for (int r = 0; r < 4; ++r) {
                    const float pr = (V == 1) ? prc : t3[-r];
                    if constexpr (V == 3) {
                        sw[g][r] = fmaf(acc[r], pr, sw[g][r]);   // acc+pr live, u-math gone
                        se[g][r] += D0;
                    } else {
                        const float s  = acc[r] * pr;
                        const float u  = fmaf(0.5f * s, s, s);
                        se[g][r] += u;
                        sw[g][r]  = fmaf(u, D0, sw[g][r]);
                    }
                }
            }
        }
    }

    // reduce each (g,r) over the 16 lanes sharing a row; stash in LDS
#pragma unroll
    for (int g = 0; g < 4; ++g)
#pragma unroll
        for (int r = 0; r < 4; ++r) {
            float e = se[g][r], w = sw[g][r];
            for (int off = 8; off >= 1; off >>= 1) {
                e += __shfl_xor(e, off, 64);
                w += __shfl_xor(w, off, 64);
            }
            if (lrow == 0) {
                float2 pv;
                pv.x = e;
                pv.y = w - (float)r * e;   // fold -r*Sigma_u correction
                comb[wave][g * 16 + kg * 4 + r] = pv;
            }
        }
    __syncthreads();

    // combine 4 key-quarters and write
    if (threadIdx.x < 64) {
        const int row = threadIdx.x;
        const int b   = bh >> 3;
        float e = 0.f, w = 0.f;
#pragma unroll
        for (int v = 0; v < 4; ++v) { e += comb[v][row].x; w += comb[v][row].y; }
        const int i = i0 + row;
        const float C = (float)(2096128 - 2048 * i);   // sum_m (m - i), exact
        outp[((size_t)(b * LB + i)) * HB + h] = (C + w) / (2048.0f + e);
    }
}

extern "C" void kernel_launch(void* const* d_in, const int* in_sizes, int n_in,
                              void* d_out, int out_size, void* d_ws, size_t ws_size,
                              hipStream_t stream) {
    const float* x  = (const float*)d_in[0];
    const float* Wq = (const float*)d_in[1];
    const float* bq = (const float*)d_in[2];
    const float* Wk = (const float*)d_in[3];
    const float* bk = (const float*)d_in[4];
    const float* pm = (const float*)d_in[5];
    const float* ls = (const float*)d_in[6];
    float* out = (float*)d_out;

    __hip_bfloat16* qbuf = (__hip_bfloat16*)d_ws;
    __hip_bfloat16* kbuf = qbuf + (size_t)BH * LB * KB;       // +8.4 MB
    __hip_bfloat16* xbuf = kbuf + (size_t)BH * LB * KB;       // +8.4 MB
    __hip_bfloat16* wbuf = xbuf + (size_t)8192 * 256;         // +4.2 MB
    // ablation scratch aliases xbuf (proj_mfma is done with it before attn runs;
    // prep_x rewrites it at the start of every call -> deterministic)
    float* scr = (float*)xbuf;

    prep_x<<<dim3(512), dim3(256), 0, stream>>>(x, xbuf);
    prep_w<<<dim3(64), dim3(256), 0, stream>>>(Wq, Wk, wbuf);
    proj_mfma<<<dim3(128, 8), dim3(256), 0, stream>>>(xbuf, wbuf, bq, bk, qbuf, kbuf);

    // ablation probes (dead outputs, timed per-dispatch by rocprof)
    attn_k<1><<<dim3(32, 32), dim3(256), 0, stream>>>(qbuf, kbuf, pm, ls, scr + 0 * 65536);
    attn_k<2><<<dim3(32, 32), dim3(256), 0, stream>>>(qbuf, kbuf, pm, ls, scr + 1 * 65536);
    attn_k<3><<<dim3(32, 32), dim3(256), 0, stream>>>(qbuf, kbuf, pm, ls, scr + 2 * 65536);
    attn_k<4><<<dim3(32, 32), dim3(256), 0, stream>>>(qbuf, kbuf, pm, ls, scr + 3 * 65536);

    // the real one
    attn_k<0><<<dim3(32, 32), dim3(256), 0, stream>>>(qbuf, kbuf, pm, ls, out);
}

// Round 11
// 66.132 us; speedup vs baseline: 2.7391x; 2.7391x over previous
//
#include <hip/hip_runtime.h>
#include <hip/hip_bf16.h>

#define LB 2048
#define DB 256
#define HB 8
#define KB 64
#define BH 32   // B*H

typedef __attribute__((ext_vector_type(8))) short short8;
typedef __attribute__((ext_vector_type(4))) short short4v;
typedef __attribute__((ext_vector_type(4))) float floatx4;

static __device__ __forceinline__ short bfbits(float f) {
    __hip_bfloat16 h = __float2bfloat16(f);
    return *reinterpret_cast<short*>(&h);
}

// async global->LDS, 16B per lane; LDS dest = uniform base + lane*16 (HW rule),
// global src = per-lane address.
static __device__ __forceinline__ void gl_lds16(const void* g, void* l) {
    __builtin_amdgcn_global_load_lds(
        (const __attribute__((address_space(1))) void*)g,
        (__attribute__((address_space(3))) void*)l, 16, 0, 0);
}

// Fragment-order formula (16-row tile, element (l, k)):
//   pos = ((k>>3)*16 + (l&15))*8 + (k&7)

// ---------------- prep: x fp32 [8192][256] -> bf16 fragment tiles [512][4096]
__global__ __launch_bounds__(256) void prep_x(const float* __restrict__ x,
                                              __hip_bfloat16* __restrict__ xb)
{
    const int t = blockIdx.x;                 // 16-row tile
#pragma unroll
    for (int cc = 0; cc < 2; ++cc) {
        const int c   = threadIdx.x + cc * 256;   // chunk 0..511
        const int l   = c & 15;
        const int ksg = c >> 4;                   // k = ksg*8 ..
        const float* src = x + (size_t)(t * 16 + l) * DB + ksg * 8;
        short8 o;
#pragma unroll
        for (int e = 0; e < 8; ++e) o[e] = bfbits(src[e]);
        *(reinterpret_cast<short8*>(xb + (size_t)t * 4096) + c) = o;
    }
}

// ---------------- prep: W [256][512] -> transposed bf16 fragment tiles
__global__ __launch_bounds__(256) void prep_w(const float* __restrict__ Wq,
                                              const float* __restrict__ Wk,
                                              __hip_bfloat16* __restrict__ wb)
{
    const int blk = blockIdx.x;               // 0..63
    const float* W = (blk & 32) ? Wk : Wq;
    const int nbase = (blk & 31) * 16;
#pragma unroll
    for (int cc = 0; cc < 2; ++cc) {
        const int c  = threadIdx.x + cc * 256;
        const int n  = nbase + (c & 15);
        const int k0 = (c >> 4) * 8;
        short8 o;
#pragma unroll
        for (int e = 0; e < 8; ++e) o[e] = bfbits(W[(size_t)(k0 + e) * 512 + n]);
        *(reinterpret_cast<short8*>(wb + (size_t)blk * 4096) + c) = o;
    }
}

// ---------------- one-time per-head prior table -> global [8][4096]
__global__ __launch_bounds__(256) void tab_build(const float* __restrict__ pm,
                                                 const float* __restrict__ ls,
                                                 float* __restrict__ tabg)
{
    const int h   = blockIdx.x >> 2;
    const int seg = blockIdx.x & 3;
    const float mu        = pm[h];
    const float inv_sigma = __expf(-ls[h]);
    const float coef = 0.125f * inv_sigma * (1.0f / 2.5066282f);
    const int j0 = seg * 1024 + threadIdx.x * 4;
    float4 o;
#pragma unroll
    for (int e = 0; e < 4; ++e) {
        const float t = ((float)(j0 + e - 2047) - mu) * inv_sigma;
        (&o.x)[e] = coef * __expf(-0.5f * t * t);
    }
    *reinterpret_cast<float4*>(tabg + (size_t)h * 4096 + j0) = o;
}

// ---------------- projection GEMM via MFMA (unchanged)
__global__ __launch_bounds__(256) void proj_mfma(
    const __hip_bfloat16* __restrict__ xb, const __hip_bfloat16* __restrict__ wb,
    const float* __restrict__ bq, const float* __restrict__ bk,
    __hip_bfloat16* __restrict__ qout, __hip_bfloat16* __restrict__ kout)
{
    const int rt   = blockIdx.x;              // 64-row block
    const int cg   = blockIdx.y;              // 128-col group
    const int wave = threadIdx.x >> 6;
    const int lane = threadIdx.x & 63;
    const int kg   = lane >> 4;
    const int l    = lane & 15;

    const short8* xp = reinterpret_cast<const short8*>(xb)
                     + (size_t)(rt * 4 + wave) * 512 + lane;
    short8 a[8];
#pragma unroll
    for (int kb = 0; kb < 8; ++kb) a[kb] = xp[kb * 64];

    const int b_     = rt >> 5;               // batch
    const int tile_l = (rt & 31) * 4 + wave;  // 16-row tile index within [B,L]
    const int gct0   = cg * 8;
    const short8* wp = reinterpret_cast<const short8*>(wb) + lane;

    short8 wA[8], wB[8];
#pragma unroll
    for (int kb = 0; kb < 8; ++kb) wA[kb] = wp[(size_t)(gct0 * 8 + kb) * 64];

#define PROJ_STEP(CURW, NXTW, CT)                                                     \
    {                                                                                 \
        if ((CT) < 7) {                                                               \
            _Pragma("unroll")                                                         \
            for (int kb = 0; kb < 8; ++kb)                                            \
                NXTW[kb] = wp[(size_t)((gct0 + (CT) + 1) * 8 + kb) * 64];             \
        }                                                                             \
        floatx4 acc = {0.f, 0.f, 0.f, 0.f};                                           \
        _Pragma("unroll")                                                             \
        for (int kb = 0; kb < 8; ++kb)                                                \
            acc = __builtin_amdgcn_mfma_f32_16x16x32_bf16(CURW[kb], a[kb], acc, 0, 0, 0); \
        const int gct = gct0 + (CT);                                                  \
        const int m   = gct >> 5;                                                     \
        const int ctm = gct & 31;                                                     \
        const int h   = ctm >> 2;                                                     \
        const float bias = (m ? bk : bq)[h];                                          \
        __hip_bfloat16* outp = m ? kout : qout;                                       \
        const size_t dst = ((size_t)(b_ * HB + h) * 128 + tile_l) * 1024              \
                         + (size_t)(((ctm & 3) * 2 + (kg >> 1)) * 16 + l) * 8         \
                         + (kg & 1) * 4;                                              \
        short4v o;                                                                    \
        _Pragma("unroll")                                                             \
        for (int r = 0; r < 4; ++r) o[r] = bfbits(acc[r] + bias);                     \
        *reinterpret_cast<short4v*>(outp + dst) = o;                                  \
    }

    PROJ_STEP(wA, wB, 0)
    PROJ_STEP(wB, wA, 1)
    PROJ_STEP(wA, wB, 2)
    PROJ_STEP(wB, wA, 3)
    PROJ_STEP(wA, wB, 4)
    PROJ_STEP(wB, wA, 5)
    PROJ_STEP(wA, wB, 6)
    PROJ_STEP(wB, wA, 7)
#undef PROJ_STEP
}

// ---------------- attention: exp-free 2nd-order softmax + distance expectation
// Block = 64 q-rows x 2048 keys. Wave w owns rows [w*16, w*16+16) (all keys).
// K staged per 64-key step into LDS via global_load_lds, double-buffered:
//   issue stage(st+1) -> ds_read+MFMA+epilogue(st) -> __syncthreads (vmcnt drain).
__global__ __launch_bounds__(256) void attn_kernel(
    const __hip_bfloat16* __restrict__ qb, const __hip_bfloat16* __restrict__ kb,
    const float* __restrict__ tabg, float* __restrict__ out)
{
    __shared__ float stab[4096];                        // 16 KB prior table
    __shared__ __align__(16) __hip_bfloat16 kt[2][4096]; // 2 x 8 KB K tiles

    const int tile = blockIdx.x;          // 64-row q tile, 0..31
    const int bh   = blockIdx.y;          // 0..31
    const int b    = bh >> 3;
    const int h    = bh & 7;
    const int wave = threadIdx.x >> 6;
    const int lane = threadIdx.x & 63;
    const int lrow = lane & 15;
    const int kg   = lane >> 4;
    const int i0w  = tile * 64 + wave * 16;   // this wave's first q row

    // coalesced LDS fill of the per-head prior table
    {
        const float4* gt = reinterpret_cast<const float4*>(tabg + (size_t)h * 4096);
        float4* st4 = reinterpret_cast<float4*>(stab);
#pragma unroll
        for (int s = 0; s < 4; ++s) st4[threadIdx.x + 256 * s] = gt[threadIdx.x + 256 * s];
    }

    const size_t planebase = (size_t)bh * LB * KB;

    // A fragments: this wave's 16 rows
    const short8* qp = reinterpret_cast<const short8*>(qb + planebase)
                     + (size_t)(tile * 4 + wave) * 128 + lane;
    const short8 a0 = qp[0];
    const short8 a1 = qp[64];

    // K plane as bytes; one 64-key step = 8192 contiguous bytes (fragment order)
    const char* kgl = reinterpret_cast<const char*>(kb + planebase);

    // wave w stages bytes [w*2048, w*2048+2048) of each step tile
#define STAGE(BI, ST)                                                                \
    {                                                                                \
        const char* g0 = kgl + (size_t)(ST) * 8192 + wave * 2048 + lane * 16;        \
        char* l0 = reinterpret_cast<char*>(&kt[BI][0]) + wave * 2048;                \
        gl_lds16(g0, l0);                                                            \
        gl_lds16(g0 + 1024, l0 + 1024);                                              \
    }

    float se[4] = {0.f, 0.f, 0.f, 0.f};
    float sw[4] = {0.f, 0.f, 0.f, 0.f};

    const int lo = lrow - 4 * kg;
    const float* tb = &stab[2047 + lo - i0w];
    const float Dl = (float)(lo - i0w);

    STAGE(0, 0)
    __syncthreads();      // stage 0 complete (vmcnt drain) + tab visible

    for (int st = 0; st < 32; ++st) {
        const int cur = st & 1;
        if (st < 31) STAGE(cur ^ 1, st + 1)

        const short8* kl = reinterpret_cast<const short8*>(&kt[cur][0]) + lane;
#pragma unroll
        for (int c = 0; c < 4; ++c) {
            const short8 kk0 = kl[c * 128];
            const short8 kk1 = kl[c * 128 + 64];
            floatx4 z = {0.f, 0.f, 0.f, 0.f};
            z = __builtin_amdgcn_mfma_f32_16x16x32_bf16(a0, kk0, z, 0, 0, 0);
            const floatx4 acc = __builtin_amdgcn_mfma_f32_16x16x32_bf16(a1, kk1, z, 0, 0, 0);

            const int   off = st * 64 + 16 * c;
            const float* t3 = tb + off;
            const float D0  = Dl + (float)off;
#pragma unroll
            for (int r = 0; r < 4; ++r) {
                const float pr = t3[-r];
                const float s  = acc[r] * pr;
                const float u  = fmaf(0.5f * s, s, s);
                se[r] += u;
                sw[r]  = fmaf(u, D0, sw[r]);
            }
        }
        __syncthreads();   // next tile staged; everyone done reading kt[cur]
    }
#undef STAGE

    // reduce over the 16 lanes sharing each output row (lane bits 0..3), write out
#pragma unroll
    for (int r = 0; r < 4; ++r) {
        float e = se[r], w = sw[r];
        for (int off = 8; off >= 1; off >>= 1) {
            e += __shfl_xor(e, off, 64);
            w += __shfl_xor(w, off, 64);
        }
        if (lrow == 0) {
            const int i = i0w + kg * 4 + r;
            const float C = (float)(2096128 - 2048 * i);   // sum_m (m - i), exact
            out[((size_t)(b * LB + i)) * HB + h] =
                (C + w - (float)r * e) / (2048.0f + e);
        }
    }
}

extern "C" void kernel_launch(void* const* d_in, const int* in_sizes, int n_in,
                              void* d_out, int out_size, void* d_ws, size_t ws_size,
                              hipStream_t stream) {
    const float* x  = (const float*)d_in[0];
    const float* Wq = (const float*)d_in[1];
    const float* bq = (const float*)d_in[2];
    const float* Wk = (const float*)d_in[3];
    const float* bk = (const float*)d_in[4];
    const float* pm = (const float*)d_in[5];
    const float* ls = (const float*)d_in[6];
    float* out = (float*)d_out;

    __hip_bfloat16* qbuf = (__hip_bfloat16*)d_ws;
    __hip_bfloat16* kbuf = qbuf + (size_t)BH * LB * KB;       // +8.4 MB
    __hip_bfloat16* xbuf = kbuf + (size_t)BH * LB * KB;       // +8.4 MB
    __hip_bfloat16* wbuf = xbuf + (size_t)8192 * 256;         // +4.2 MB
    float*          tabg = (float*)(wbuf + (size_t)64 * 4096); // +0.5 MB, then 128 KB

    prep_x<<<dim3(512), dim3(256), 0, stream>>>(x, xbuf);
    prep_w<<<dim3(64), dim3(256), 0, stream>>>(Wq, Wk, wbuf);
    tab_build<<<dim3(32), dim3(256), 0, stream>>>(pm, ls, tabg);
    proj_mfma<<<dim3(128, 8), dim3(256), 0, stream>>>(xbuf, wbuf, bq, bk, qbuf, kbuf);
    attn_kernel<<<dim3(32, 32), dim3(256), 0, stream>>>(qbuf, kbuf, tabg, out);
}